// Round 15
// baseline (584.595 us; speedup 1.0000x reference)
//
#include <hip/hip_runtime.h>

// Palettized 3x3 VALID conv as implicit GEMM:
//   C[M=16*254*254, 64] = A[M, K=576] * B[K=576, 64],  K = (kh*3+kw)*64 + c
// Round-15: R14 (175us) + 2-TILE PERSISTENT PIPELINE. R14 accounting: block
// lifetime ~22us vs ~5.6us HBM-share + ~4.5us LDS + ~1.2us MFMA -> >half is
// per-block fixed serial cost (prologue latency, barriers, epilogue tail),
// paid 4064x. Fix: each block does BOTH ow-tiles of its (n,ohp): channel
// halves commute, so tile1 runs h1->h0 and reuses tile0's final breg (odd-B)
// -- no-VMEM-in-kc-loop preserved. Tile1 prefetches issue under tile0
// compute; tile0 stores drain under tile1 compute (prefA issued BEFORE the
// stores so writeA's pf-wait leaves stores outstanding). Slab in a DISJOINT
// LDS region (67.2KB total, still 2 blocks/CU) so epilogue no longer
// serializes with A-staging. All components R14-verbatim; schedule only.

typedef __bf16 bf16x8 __attribute__((ext_vector_type(8)));
typedef float f32x4 __attribute__((ext_vector_type(4)));
typedef float f32x2 __attribute__((ext_vector_type(2)));

union Frag {
    uint4 q;
    bf16x8 v;
};

#define LGKM_BARRIER() do { \
    asm volatile("s_waitcnt lgkmcnt(0)" ::: "memory"); \
    __builtin_amdgcn_s_barrier(); \
    asm volatile("" ::: "memory"); } while (0)

// ---- B dequant/swizzle: Bws[s]  s = (kc*4 + nt)*64 + lane, 16B per slot.
__global__ __launch_bounds__(256) void dequant_B(
        const float* __restrict__ lut, const int* __restrict__ widx,
        uint4* __restrict__ Bws) {
    int s = blockIdx.x * 256 + threadIdx.x;   // 0..4607
    int l = s & 63;
    int nt = (s >> 6) & 3;
    int kc = s >> 8;
    if (kc >= 18) return;
    int r = kc >> 1;
    int kh = r / 3, kw = r - kh * 3;
    int o = nt * 16 + (l & 15);
    int c0 = (kc & 1) * 32 + (l >> 4) * 8;
    Frag f;
#pragma unroll
    for (int j = 0; j < 8; ++j) {
        int c = c0 + j;
        int idx = widx[((o * 64 + c) * 3 + kh) * 3 + kw];
        f.v[j] = (__bf16)lut[idx];
    }
    Bws[s] = f.q;
}

// LDS: ldsA[cbl][pix] 16B granules; pix = row*132 + col (rows 0..3, cols
// 0..129, pitch 132); cbl stride A_CB=530. granule = 8 bf16 channels, u32
// word chp = packed (ch 2chp, 2chp+1). Slab region disjoint after ldsA.
#define A_CB 530

__global__ __launch_bounds__(256, 2) void conv_mfma(
        const float* __restrict__ x, const float* __restrict__ bias,
        const uint4* __restrict__ Bws, float* __restrict__ out) {
    __shared__ uint4 lds[4200];           // 67200 B: [0,2120)=A, rest slab
    uint4* ldsA = lds;
    unsigned* lds32 = (unsigned*)lds;

    int bx = blockIdx.x;                  // 0..2031
    int ohp = bx % 127;
    int n   = bx / 127;
    int oh0 = ohp * 2;                    // rows oh0, oh0+1
    int t = threadIdx.x;

    const float* xn = x + (size_t)n * (64 * 256 * 256);

    int w = t >> 6;                       // wave 0..3
    int l = t & 63;
    int l15 = l & 15, l4 = l >> 4;

    // tail staging roles (cols 128,129 of the tile): t<32
    int tl_cb  = t & 3;
    int tl_rc  = t >> 2;                  // 0..7 for t<32
    int tl_rr  = tl_rc >> 1;              // 0..3
    int tl_col = 128 + (tl_rc & 1);

    int ohl = w >> 1;                     // wave's oh row in tile (0..1)
    int ob  = (w & 1) * 2;                // wave's B nt-offset (O-half)

    f32x4 acc[8][2] = {};
    uint4 breg[18];
    f32x4 pf0[8], pf1[8];
    float tpre[8];

    auto loadB = [&](int h) {
#pragma unroll
        for (int i = 0; i < 9; ++i) {
            int kc = 2 * i + h;
            breg[i * 2 + 0] = Bws[(kc * 4 + ob + 0) * 64 + l];
            breg[i * 2 + 1] = Bws[(kc * 4 + ob + 1) * 64 + l];
        }
    };

    auto prefA = [&](int h, int ow0) {
        const float* cbase = xn + (size_t)((h * 4 + w) * 8 + l4 * 2) * 65536 + ow0;
#pragma unroll
        for (int ch2 = 0; ch2 < 2; ++ch2) {
            const float* pb = cbase + ch2 * 64 + l15 * 4;
#pragma unroll
            for (int rr = 0; rr < 4; ++rr) {
                const float* p = pb + (oh0 + rr) * 256;
                pf0[ch2 * 4 + rr] = *(const f32x4*)(p);
                pf1[ch2 * 4 + rr] = *(const f32x4*)(p + 65536);
            }
        }
        if (t < 32) {
            int xc = ow0 + tl_col; if (xc > 255) xc = 255;
            const float* src = xn + (size_t)((h * 4 + tl_cb) * 8) * 65536
                               + (oh0 + tl_rr) * 256 + xc;
#pragma unroll
            for (int j = 0; j < 8; ++j)
                tpre[j] = src[j * 65536];
        }
    };

    auto writeA = [&]() {
#pragma unroll
        for (int ch2 = 0; ch2 < 2; ++ch2)
#pragma unroll
            for (int rr = 0; rr < 4; ++rr) {
                int gbase = w * A_CB + rr * 132 + ch2 * 64 + l15 * 4;
#pragma unroll
                for (int i = 0; i < 4; ++i) {
                    union { __bf16 hh[2]; unsigned u; } bp;
                    bp.hh[0] = (__bf16)pf0[ch2 * 4 + rr][i];
                    bp.hh[1] = (__bf16)pf1[ch2 * 4 + rr][i];
                    lds32[(gbase + i) * 4 + l4] = bp.u;
                }
            }
        if (t < 32) {
            Frag f;
#pragma unroll
            for (int j = 0; j < 8; ++j)
                f.v[j] = (__bf16)tpre[j];
            ldsA[tl_cb * A_CB + tl_rr * 132 + tl_col] = f.q;
        }
    };

    auto compute = [&]() {
#pragma unroll
        for (int i = 0; i < 9; ++i) {
            int kh = i / 3, kw = i - kh * 3;       // compile-time
            Frag b0, b1;
            b0.q = breg[i * 2 + 0];
            b1.q = breg[i * 2 + 1];
            Frag a[8];
#pragma unroll
            for (int mt = 0; mt < 8; ++mt)
                a[mt].q = ldsA[l4 * A_CB + (ohl + kh) * 132 + l15 + kw + mt * 16];
#pragma unroll
            for (int mt = 0; mt < 8; ++mt) {
                acc[mt][0] = __builtin_amdgcn_mfma_f32_16x16x32_bf16(
                    a[mt].v, b0.v, acc[mt][0], 0, 0, 0);
                acc[mt][1] = __builtin_amdgcn_mfma_f32_16x16x32_bf16(
                    a[mt].v, b1.v, acc[mt][1], 0, 0, 0);
            }
        }
    };

    // slab: disjoint region; 16x130 f32 per wave
    float* slab = (float*)(lds + 4 * A_CB) + w * 2080;
    int oseg = (w & 1) * 32;
    int oh = oh0 + ohl;

    auto scatter = [&]() {                // acc -> slab (wave-private, no barrier)
#pragma unroll
        for (int nt = 0; nt < 2; ++nt)
#pragma unroll
            for (int mt = 0; mt < 8; ++mt)
#pragma unroll
                for (int rg = 0; rg < 4; ++rg)
                    slab[nt * 1040 + l15 * 65 + ((mt * 16 + l4 * 4 + rg) >> 1)
                         * 0 + 0] = 0;    // placeholder never used
    };
    (void)scatter;

    auto scatter2 = [&]() {               // real scatter: [nt][o16][ow128] pitch 130
#pragma unroll
        for (int nt = 0; nt < 2; ++nt)
#pragma unroll
            for (int mt = 0; mt < 8; ++mt)
#pragma unroll
                for (int rg = 0; rg < 4; ++rg)
                    slab[l15 * 130 + mt * 16 + l4 * 4 + rg + nt * 0] =
                        acc[mt][nt][rg];  // overwritten per nt in gather order
    };
    (void)scatter2;

    // NOTE: scatter+gather must be interleaved per nt (slab holds one nt at a
    // time, 16x130). Done inline in gstore below.
    auto gstore = [&](int ow0) {
        float* orow = out + ((size_t)n * 64 * 254 + oh) * 254 + ow0;
        bool ok = (ow0 + l * 2 + 1) < 254;
#pragma unroll
        for (int nt = 0; nt < 2; ++nt) {
#pragma unroll
            for (int mt = 0; mt < 8; ++mt)
#pragma unroll
                for (int rg = 0; rg < 4; ++rg)
                    slab[l15 * 130 + mt * 16 + l4 * 4 + rg] = acc[mt][nt][rg];
#pragma unroll
            for (int j = 0; j < 16; ++j) {
                int o = oseg + nt * 16 + j;
                float bv = bias[o];
                f32x2 v;
                v[0] = slab[j * 130 + l * 2]     + bv;
                v[1] = slab[j * 130 + l * 2 + 1] + bv;
                if (ok)
                    *(f32x2*)(orow + (size_t)o * (254 * 254) + l * 2) = v;
            }
        }
    };

    auto zacc = [&]() {
#pragma unroll
        for (int mt = 0; mt < 8; ++mt)
#pragma unroll
            for (int nt = 0; nt < 2; ++nt)
                acc[mt][nt] = f32x4{0.f, 0.f, 0.f, 0.f};
    };

    // ================= 2-tile pipeline (T0: ow0=0, T1: ow0=128) =============
    loadB(0);
    prefA(0, 0);               // T0 h0
    writeA();
    LGKM_BARRIER();
    prefA(1, 0);               // T0 h1 in flight
    compute();                 // T0 h0 (breg even)
    loadB(1);
    LGKM_BARRIER();            // ldsA reads done
    writeA();                  // T0 h1
    LGKM_BARRIER();
    prefA(1, 128);             // T1 h1 in flight (pf free: consumed by writeA)
    compute();                 // T0 h1 (breg odd)
    LGKM_BARRIER();            // ldsA reads done before overwrite
    writeA();                  // T1 h1
    LGKM_BARRIER();
    prefA(0, 128);             // T1 h0 in flight (BEFORE stores: pf-wait can
                               // leave the newer stores outstanding)
    gstore(0);                 // T0 epilogue: slab (disjoint) + stores drain
    zacc();                    //   under T1 compute
    compute();                 // T1 h1 (breg odd, reused)
    loadB(0);
    LGKM_BARRIER();
    writeA();                  // T1 h0
    LGKM_BARRIER();
    compute();                 // T1 h0 (breg even)
    gstore(128);               // T1 epilogue
}

extern "C" void kernel_launch(void* const* d_in, const int* in_sizes, int n_in,
                              void* d_out, int out_size, void* d_ws, size_t ws_size,
                              hipStream_t stream) {
    const float* x    = (const float*)d_in[0];
    const float* lut  = (const float*)d_in[1];
    const int*   widx = (const int*)d_in[2];
    const float* bias = (const float*)d_in[3];
    float* out = (float*)d_out;
    uint4* Bws = (uint4*)d_ws;   // needs 73728 B

    dequant_B<<<18, 256, 0, stream>>>(lut, widx, Bws);
    conv_mfma<<<16 * 127, 256, 0, stream>>>(x, bias, (const uint4*)Bws, out);
}